// Round 1
// baseline (340.094 us; speedup 1.0000x reference)
//
#include <hip/hip_runtime.h>

#define DEVI __device__ __forceinline__

typedef unsigned short u16;
typedef unsigned int u32;

using bf16x8 = __attribute__((ext_vector_type(8))) short;
using f32x4  = __attribute__((ext_vector_type(4))) float;

DEVI u16 f2bf(float f) {
  u32 u = __builtin_bit_cast(u32, f);
  u32 r = (u + 0x7fffu + ((u >> 16) & 1u)) >> 16;
  return (u16)r;
}

DEVI void gl_lds16(const u16* g, u16* l) {
  __builtin_amdgcn_global_load_lds(
      (const __attribute__((address_space(1))) u32*)g,
      (__attribute__((address_space(3))) u32*)l, 16, 0, 0);
}

// ---------------- LayerNorm + bf16 cast ----------------
// grid: 32*1088 blocks, 256 threads. Row r<1024 -> x row (g_media), else latent row (g_lat).
// Writes kvin[32*1088][1024]; latent rows also duplicated into latb[32*64][1024].
__global__ __launch_bounds__(256) void ln_kernel(
    const float* __restrict__ x, const float* __restrict__ lat,
    const float* __restrict__ gm, const float* __restrict__ bm,
    const float* __restrict__ gl, const float* __restrict__ bl,
    u16* __restrict__ kvin, u16* __restrict__ latb)
{
  int row = blockIdx.x;
  int bt = row / 1088, r = row % 1088;
  const float *src, *g, *b;
  bool is_lat = (r >= 1024);
  if (!is_lat) { src = x + ((size_t)bt*1024 + r)*1024; g = gm; b = bm; }
  else         { src = lat + ((size_t)bt*64 + (r-1024))*1024; g = gl; b = bl; }
  int tid = threadIdx.x;
  float4 v = *(const float4*)(src + tid*4);
  float s1 = v.x+v.y+v.z+v.w;
  float s2 = v.x*v.x+v.y*v.y+v.z*v.z+v.w*v.w;
  for (int off=32; off; off>>=1){ s1 += __shfl_down(s1,off); s2 += __shfl_down(s2,off); }
  __shared__ float red[2][4];
  int w = tid>>6, lane = tid&63;
  if (lane==0){ red[0][w]=s1; red[1][w]=s2; }
  __syncthreads();
  s1 = red[0][0]+red[0][1]+red[0][2]+red[0][3];
  s2 = red[1][0]+red[1][1]+red[1][2]+red[1][3];
  float mu = s1 * (1.f/1024.f);
  float var = s2 * (1.f/1024.f) - mu*mu;
  float rstd = rsqrtf(var + 1e-5f);
  float4 gv = *(const float4*)(g + tid*4);
  float4 bv = *(const float4*)(b + tid*4);
  ushort4 o;
  o.x = f2bf((v.x-mu)*rstd*gv.x + bv.x);
  o.y = f2bf((v.y-mu)*rstd*gv.y + bv.y);
  o.z = f2bf((v.z-mu)*rstd*gv.z + bv.z);
  o.w = f2bf((v.w-mu)*rstd*gv.w + bv.w);
  *(ushort4*)(kvin + (size_t)row*1024 + tid*4) = o;
  if (is_lat) *(ushort4*)(latb + ((size_t)(bt*64 + (r-1024)))*1024 + tid*4) = o;
}

// ---------------- transpose f32 -> bf16 (out[C][R] = in[R][C]) ----------------
__global__ __launch_bounds__(256) void transpose_cast(
    const float* __restrict__ in, u16* __restrict__ out, int R, int C)
{
  __shared__ float t[32][33];
  int bx = blockIdx.x*32, by = blockIdx.y*32;
  int tx = threadIdx.x & 31, ty = threadIdx.x >> 5;   // 32 x 8
  for (int k=0;k<32;k+=8) t[ty+k][tx] = in[(size_t)(by+ty+k)*C + bx+tx];
  __syncthreads();
  for (int k=0;k<32;k+=8) out[(size_t)(bx+ty+k)*R + by+tx] = f2bf(t[tx][ty+k]);
}

// ---------------- m97-style 128x128 bf16 GEMM, B^T operand ----------------
// MODE 0: bf16 C row-major (ld = N), scaled. MODE 1: f32 C. MODE 2: kv split
//   (cols <1024 -> k row-major into C0 ld=1024; cols >=1024 -> v transposed into C1 [bt*1024+d][1088]).
template<int MODE>
__global__ __launch_bounds__(256,2) void gemm_bt(
    const u16* __restrict__ A, const u16* __restrict__ BT,
    void* __restrict__ C0, void* __restrict__ C1,
    int M, int N, int K, float scale)
{
  __shared__ u16 lA[128*32];
  __shared__ u16 lB[128*32];
  int tid = threadIdx.x;
  int w = tid>>6, lane = tid&63;
  int li = lane&15, lg = lane>>4;
  int m0 = blockIdx.y*128, n0 = blockIdx.x*128;
  int wr = (w>>1)*64, wc = (w&1)*64;
  f32x4 acc[4][4] = {};
  int sr = lane>>2;          // 0..15
  int sk = (lane&3)*8;
  const u16* pa = A  + (size_t)(m0 + w*32 + sr)*K + sk;
  const u16* pb = BT + (size_t)(n0 + w*32 + sr)*K + sk;
  u16* la0 = lA + (w*2)*512; u16* la1 = lA + (w*2+1)*512;
  u16* lb0 = lB + (w*2)*512; u16* lb1 = lB + (w*2+1)*512;
  for (int k0=0; k0<K; k0+=32) {
    gl_lds16(pa,        la0);
    gl_lds16(pa + 16*(size_t)K, la1);
    gl_lds16(pb,        lb0);
    gl_lds16(pb + 16*(size_t)K, lb1);
    pa += 32; pb += 32;
    __syncthreads();
    bf16x8 af[4], bfr[4];
    #pragma unroll
    for (int m=0;m<4;++m) af[m]  = *(const bf16x8*)(lA + (wr + m*16 + li)*32 + lg*8);
    #pragma unroll
    for (int n=0;n<4;++n) bfr[n] = *(const bf16x8*)(lB + (wc + n*16 + li)*32 + lg*8);
    #pragma unroll
    for (int m=0;m<4;++m)
      #pragma unroll
      for (int n=0;n<4;++n)
        acc[m][n] = __builtin_amdgcn_mfma_f32_16x16x32_bf16(af[m], bfr[n], acc[m][n], 0,0,0);
    __syncthreads();
  }
  // epilogue: C layout col=lane&15, row=(lane>>4)*4+reg
  if (MODE == 0) {
    u16* C = (u16*)C0;
    #pragma unroll
    for (int m=0;m<4;++m)
      #pragma unroll
      for (int n=0;n<4;++n) {
        int row = m0 + wr + m*16 + lg*4;
        int col = n0 + wc + n*16 + li;
        #pragma unroll
        for (int rg=0;rg<4;++rg)
          C[(size_t)(row+rg)*N + col] = f2bf(acc[m][n][rg]*scale);
      }
  } else if (MODE == 1) {
    float* C = (float*)C0;
    #pragma unroll
    for (int m=0;m<4;++m)
      #pragma unroll
      for (int n=0;n<4;++n) {
        int row = m0 + wr + m*16 + lg*4;
        int col = n0 + wc + n*16 + li;
        #pragma unroll
        for (int rg=0;rg<4;++rg)
          C[(size_t)(row+rg)*N + col] = acc[m][n][rg]*scale;
      }
  } else {
    if (n0 < 1024) {
      u16* kb = (u16*)C0;
      #pragma unroll
      for (int m=0;m<4;++m)
        #pragma unroll
        for (int n=0;n<4;++n) {
          int row = m0 + wr + m*16 + lg*4;
          int col = n0 + wc + n*16 + li;
          #pragma unroll
          for (int rg=0;rg<4;++rg)
            kb[(size_t)(row+rg)*1024 + col] = f2bf(acc[m][n][rg]);
        }
    } else {
      u16* vt = (u16*)C1;
      #pragma unroll
      for (int m=0;m<4;++m)
        #pragma unroll
        for (int n=0;n<4;++n) {
          int r0 = m0 + wr + m*16 + lg*4;            // 4 consecutive rows, same bt (1088%4==0)
          int c  = n0 + wc + n*16 + li - 1024;
          int bt = r0 / 1088; int j = r0 - bt*1088;
          ushort4 o;
          o.x = f2bf(acc[m][n][0]); o.y = f2bf(acc[m][n][1]);
          o.z = f2bf(acc[m][n][2]); o.w = f2bf(acc[m][n][3]);
          *(ushort4*)(vt + ((size_t)(bt*1024 + c))*1088 + j) = o;
        }
    }
  }
}

// ---------------- MFMA flash attention ----------------
// grid 512 = (bt,h); 4 waves, each owns 16 queries, all 1088 keys (17 chunks of 64).
// sim^T = mfma(K_frag, Q_frag) so softmax reduction is shuffle-local; P via per-wave LDS tile.
__global__ __launch_bounds__(256,2) void attn_kernel(
    const u16* __restrict__ qbuf, const u16* __restrict__ kbuf,
    const u16* __restrict__ vT, u16* __restrict__ aout)
{
  __shared__ u16 p_im[4][16][72];   // row stride 144B (16B aligned)
  int blk = blockIdx.x;
  int bt = blk >> 4, h = blk & 15;
  int w = threadIdx.x>>6, lane = threadIdx.x&63;
  int li = lane&15, lg = lane>>4;
  const u16* qrow = qbuf + ((size_t)(bt*64 + w*16 + li))*1024 + h*64;
  bf16x8 qf0 = *(const bf16x8*)(qrow + lg*8);
  bf16x8 qf1 = *(const bf16x8*)(qrow + 32 + lg*8);
  float mrun = -INFINITY, lrun = 0.f;
  f32x4 oacc[4] = {};
  const u16* kbase = kbuf + (size_t)bt*1088*1024 + h*64;
  const u16* vbase = vT + ((size_t)(bt*1024 + h*64))*1088;
  for (int c=0; c<17; ++c) {
    int j0 = c*64;
    f32x4 s[4] = {};
    #pragma unroll
    for (int jt=0; jt<4; ++jt) {
      const u16* krow = kbase + (size_t)(j0 + jt*16 + li)*1024;
      bf16x8 k0 = *(const bf16x8*)(krow + lg*8);
      bf16x8 k1 = *(const bf16x8*)(krow + 32 + lg*8);
      s[jt] = __builtin_amdgcn_mfma_f32_16x16x32_bf16(k0, qf0, s[jt], 0,0,0);
      s[jt] = __builtin_amdgcn_mfma_f32_16x16x32_bf16(k1, qf1, s[jt], 0,0,0);
    }
    // lane holds sim^T[j = j0+jt*16+lg*4+rg][query w*16+li]
    float cm = -INFINITY;
    #pragma unroll
    for (int jt=0;jt<4;++jt) {
      cm = fmaxf(cm, fmaxf(fmaxf(s[jt][0], s[jt][1]), fmaxf(s[jt][2], s[jt][3])));
    }
    cm = fmaxf(cm, __shfl_xor(cm,16));
    cm = fmaxf(cm, __shfl_xor(cm,32));
    float mnew = fmaxf(mrun, cm);
    float sf = __expf(mrun - mnew);   // -inf -> 0 on first chunk
    float ls = 0.f;
    #pragma unroll
    for (int jt=0;jt<4;++jt) {
      float p0 = __expf(s[jt][0]-mnew), p1 = __expf(s[jt][1]-mnew);
      float p2 = __expf(s[jt][2]-mnew), p3 = __expf(s[jt][3]-mnew);
      ls += p0+p1+p2+p3;
      ushort4 pk; pk.x = f2bf(p0); pk.y = f2bf(p1); pk.z = f2bf(p2); pk.w = f2bf(p3);
      *(ushort4*)&p_im[w][li][jt*16 + lg*4] = pk;
    }
    ls += __shfl_xor(ls,16);
    ls += __shfl_xor(ls,32);
    lrun = lrun*sf + ls;
    mrun = mnew;
    // rescale O accumulator: its rows are i = lg*4+rg; sf lives at lane (i) (li==i group)
    float sfr[4];
    #pragma unroll
    for (int rg=0;rg<4;++rg) sfr[rg] = __shfl(sf, lg*4+rg);
    #pragma unroll
    for (int dt=0;dt<4;++dt) {
      oacc[dt][0]*=sfr[0]; oacc[dt][1]*=sfr[1]; oacc[dt][2]*=sfr[2]; oacc[dt][3]*=sfr[3];
    }
    bf16x8 pa0 = *(const bf16x8*)&p_im[w][li][lg*8];
    bf16x8 pa1 = *(const bf16x8*)&p_im[w][li][32 + lg*8];
    #pragma unroll
    for (int dt=0;dt<4;++dt) {
      const u16* vrow = vbase + (size_t)(dt*16 + li)*1088 + j0;
      bf16x8 v0 = *(const bf16x8*)(vrow + lg*8);
      bf16x8 v1 = *(const bf16x8*)(vrow + 32 + lg*8);
      oacc[dt] = __builtin_amdgcn_mfma_f32_16x16x32_bf16(pa0, v0, oacc[dt], 0,0,0);
      oacc[dt] = __builtin_amdgcn_mfma_f32_16x16x32_bf16(pa1, v1, oacc[dt], 0,0,0);
    }
  }
  float linv[4];
  #pragma unroll
  for (int rg=0;rg<4;++rg) linv[rg] = 1.f / __shfl(lrun, lg*4+rg);
  u16* orow = aout + ((size_t)(bt*64 + w*16))*1024 + h*64;
  #pragma unroll
  for (int dt=0;dt<4;++dt)
    #pragma unroll
    for (int rg=0;rg<4;++rg)
      orow[(size_t)(lg*4+rg)*1024 + dt*16 + li] = f2bf(oacc[dt][rg]*linv[rg]);
}

// ---------------- launch ----------------
extern "C" void kernel_launch(void* const* d_in, const int* in_sizes, int n_in,
                              void* d_out, int out_size, void* d_ws, size_t ws_size,
                              hipStream_t stream) {
  const float* x   = (const float*)d_in[0];
  const float* lat = (const float*)d_in[1];
  const float* gm  = (const float*)d_in[2];
  const float* bm  = (const float*)d_in[3];
  const float* gl  = (const float*)d_in[4];
  const float* bl  = (const float*)d_in[5];
  const float* Wq  = (const float*)d_in[6];
  const float* Wkv = (const float*)d_in[7];
  const float* Wo  = (const float*)d_in[8];
  float* out = (float*)d_out;

  char* ws = (char*)d_ws;
  const size_t KV_BYTES = (size_t)32*1088*1024*2;   // 71,303,168
  u16* kvin = (u16*)(ws);
  u16* kbuf = (u16*)(ws + KV_BYTES);
  u16* vT   = (u16*)(ws + 2*KV_BYTES);
  u16* latb = (u16*)(ws + 3*KV_BYTES);
  u16* qbuf = (u16*)(ws + 3*KV_BYTES + (size_t)4194304);
  u16* aout = (u16*)(ws + 3*KV_BYTES + (size_t)2*4194304);
  u16* wqT  = (u16*)(ws + 3*KV_BYTES + (size_t)3*4194304);
  u16* wkvT = (u16*)(ws + 3*KV_BYTES + (size_t)3*4194304 + 2097152);
  u16* woT  = (u16*)(ws + 3*KV_BYTES + (size_t)3*4194304 + 2097152 + 4194304);

  ln_kernel<<<dim3(32*1088), dim3(256), 0, stream>>>(x, lat, gm, bm, gl, bl, kvin, latb);
  transpose_cast<<<dim3(32,32), dim3(256), 0, stream>>>(Wq,  wqT,  1024, 1024);
  transpose_cast<<<dim3(64,32), dim3(256), 0, stream>>>(Wkv, wkvT, 1024, 2048);
  transpose_cast<<<dim3(32,32), dim3(256), 0, stream>>>(Wo,  woT,  1024, 1024);

  const float SCALE = 0.125f;   // 64^-0.5
  gemm_bt<0><<<dim3(8,16),  dim3(256), 0, stream>>>(latb, wqT,  (void*)qbuf, nullptr, 2048, 1024, 1024, SCALE);
  gemm_bt<2><<<dim3(16,272),dim3(256), 0, stream>>>(kvin, wkvT, (void*)kbuf, (void*)vT, 34816, 2048, 1024, 1.f);
  attn_kernel<<<dim3(512), dim3(256), 0, stream>>>(qbuf, kbuf, vT, aout);
  gemm_bt<1><<<dim3(8,16),  dim3(256), 0, stream>>>(aout, woT, (void*)out, nullptr, 2048, 1024, 1024, 1.f);
}